// Round 14
// baseline (2683.661 us; speedup 1.0000x reference)
//
#include <hip/hip_runtime.h>

#define B_ 64
#define T_ 4096
#define D_ 256
#define N_ 64

typedef float f32x16 __attribute__((ext_vector_type(16)));

// ---------------- misc: lens + trans copy ----------------
__global__ __launch_bounds__(64) void k_misc(const unsigned char* __restrict__ mask,
                                             const float* __restrict__ trans,
                                             float* __restrict__ out_lens,
                                             float* __restrict__ out_trans,
                                             int* __restrict__ lens_i) {
  int blk = blockIdx.x, lane = threadIdx.x;
  if (blk < B_) {
    int probe = (int)mask[0] + (int)mask[1] + (int)mask[2] + (int)mask[3];
    int cnt = 0;
    if (probe >= 2) {
      const unsigned char* row = mask + (size_t)blk * T_;
      for (int i = lane; i < T_; i += 64) cnt += row[i] ? 1 : 0;
    } else {
      const int* rowi = (const int*)mask + (size_t)blk * T_;
      for (int i = lane; i < T_; i += 64) cnt += rowi[i] ? 1 : 0;
    }
    #pragma unroll
    for (int off = 32; off > 0; off >>= 1) cnt += __shfl_down(cnt, off, 64);
    if (lane == 0) { out_lens[blk] = (float)cnt; lens_i[blk] = cnt; }
  } else {
    int base = (blk - B_) * 1024;
    for (int i = lane; i < 1024; i += 64) out_trans[base + i] = trans[base + i];
  }
}

// ---------------- projection: pot = x@W + b (+ boundaries), LDS-staged x ----------
// (r5 version, proven ~55us)
__global__ __launch_bounds__(256, 2) void k_gemm(const float* __restrict__ x,
                                                 const float* __restrict__ W,
                                                 const float* __restrict__ bias,
                                                 const float* __restrict__ lb,
                                                 const float* __restrict__ rb,
                                                 float* __restrict__ pot) {
  __shared__ float xs[64 * D_];            // 64 KB
  int tid = threadIdx.x;
  int wid = tid >> 6, lane = tid & 63;
  size_t row0 = (size_t)blockIdx.x * 64;

  const float* xb = x + row0 * D_;
  #pragma unroll
  for (int i = 0; i < 16; ++i) {
    int r = wid * 16 + i;
    float4 v = *reinterpret_cast<const float4*>(xb + (size_t)r * D_ + lane * 4);
    *reinterpret_cast<float4*>(&xs[r * D_ + lane * 4]) = v;
  }
  __syncthreads();

  float bv = bias[lane];
  float lbv = lb[lane];
  float rbv = rb[lane];

  float acc[16];
  #pragma unroll
  for (int r = 0; r < 16; ++r) {
    int t = (int)((row0 + wid * 16 + r) & (T_ - 1));
    float a = bv;
    if (t == 0)      a += lbv;
    if (t == T_ - 1) a += rbv;
    acc[r] = a;
  }

  #pragma unroll
  for (int c = 0; c < 4; ++c) {
    float w[64];
    #pragma unroll
    for (int k = 0; k < 64; ++k) w[k] = W[(size_t)(c * 64 + k) * N_ + lane];
    #pragma unroll
    for (int r = 0; r < 16; ++r) {
      const float4* xr = reinterpret_cast<const float4*>(&xs[(wid * 16 + r) * D_ + c * 64]);
      #pragma unroll
      for (int q = 0; q < 16; ++q) {
        float4 xv = xr[q];
        acc[r] += xv.x * w[q * 4 + 0];
        acc[r] += xv.y * w[q * 4 + 1];
        acc[r] += xv.z * w[q * 4 + 2];
        acc[r] += xv.w * w[q * 4 + 3];
      }
    }
  }

  #pragma unroll
  for (int r = 0; r < 16; ++r)
    pot[(row0 + wid * 16 + r) * N_ + lane] = acc[r];
}

// ---------------- fused forward + backpointers (single wave, r3 loop) ----------
// Critical path identical to r3: LDS broadcast -> float2 adds -> max3 value
// tree -> state -> ds_write. The first-index binary argmax tree (r2/r10
// verified) only feeds the bp byte store — no dependency into the recurrence —
// so it issues in the ~350cy/step latency-stall shadow. No states[] array.
#define FWD_STEP(TIDX, PREG)                                                      \
  {                                                                               \
    float pot_t = PREG;                                                           \
    int tp = (TIDX) + 4; if (tp > T_ - 1) tp = T_ - 1;                            \
    PREG = pb[(size_t)tp * N_ + lane];                                            \
    float m[64];                                                                  \
    _Pragma("unroll")                                                             \
    for (int g = 0; g < 16; ++g) {                                                \
      float4 s4 = st4v[g];                                                        \
      float2 ca = make_float2(s4.x, s4.y) + t2[2 * g];                            \
      float2 cb = make_float2(s4.z, s4.w) + t2[2 * g + 1];                        \
      m[4 * g + 0] = ca.x; m[4 * g + 1] = ca.y;                                   \
      m[4 * g + 2] = cb.x; m[4 * g + 3] = cb.y;                                   \
    }                                                                             \
    /* value: max3 tree (critical path, r3 exact) */                              \
    float r1[22];                                                                 \
    _Pragma("unroll")                                                             \
    for (int i = 0; i < 21; ++i)                                                  \
      r1[i] = fmaxf(fmaxf(m[3 * i], m[3 * i + 1]), m[3 * i + 2]);                 \
    r1[21] = m[63];                                                               \
    float r2[8];                                                                  \
    _Pragma("unroll")                                                             \
    for (int i = 0; i < 7; ++i)                                                   \
      r2[i] = fmaxf(fmaxf(r1[3 * i], r1[3 * i + 1]), r1[3 * i + 2]);              \
    r2[7] = r1[21];                                                               \
    float r3a = fmaxf(fmaxf(r2[0], r2[1]), r2[2]);                                \
    float r3b = fmaxf(fmaxf(r2[3], r2[4]), r2[5]);                                \
    float r3c = fmaxf(r2[6], r2[7]);                                              \
    float best = fmaxf(fmaxf(r3a, r3b), r3c);                                     \
    float ns = pot_t + best;                                                      \
    state = ((TIDX) < len_b) ? ns : state;                                        \
    /* index: first-index binary tree (off critical path, r2/r10 verified) */     \
    float v1[32]; int i1[32];                                                     \
    _Pragma("unroll")                                                             \
    for (int i = 0; i < 32; ++i) {                                                \
      bool g = m[2 * i + 1] > m[2 * i];                                           \
      v1[i] = g ? m[2 * i + 1] : m[2 * i];                                        \
      i1[i] = g ? 2 * i + 1 : 2 * i;                                              \
    }                                                                             \
    float v2[16]; int i2[16];                                                     \
    _Pragma("unroll")                                                             \
    for (int i = 0; i < 16; ++i) {                                                \
      bool g = v1[2 * i + 1] > v1[2 * i];                                         \
      v2[i] = g ? v1[2 * i + 1] : v1[2 * i];                                      \
      i2[i] = g ? i1[2 * i + 1] : i1[2 * i];                                      \
    }                                                                             \
    float v3[8]; int i3[8];                                                       \
    _Pragma("unroll")                                                             \
    for (int i = 0; i < 8; ++i) {                                                 \
      bool g = v2[2 * i + 1] > v2[2 * i];                                         \
      v3[i] = g ? v2[2 * i + 1] : v2[2 * i];                                      \
      i3[i] = g ? i2[2 * i + 1] : i2[2 * i];                                      \
    }                                                                             \
    float v4[4]; int i4[4];                                                       \
    _Pragma("unroll")                                                             \
    for (int i = 0; i < 4; ++i) {                                                 \
      bool g = v3[2 * i + 1] > v3[2 * i];                                         \
      v4[i] = g ? v3[2 * i + 1] : v3[2 * i];                                      \
      i4[i] = g ? i3[2 * i + 1] : i3[2 * i];                                      \
    }                                                                             \
    bool ga = v4[1] > v4[0];                                                      \
    float va = ga ? v4[1] : v4[0]; int ia = ga ? i4[1] : i4[0];                    \
    bool gb = v4[3] > v4[2];                                                      \
    float vb = gb ? v4[3] : v4[2]; int ib = gb ? i4[3] : i4[2];                    \
    int bpi = (vb > va) ? ib : ia;                                                \
    bpb[(size_t)(TIDX) * N_ + lane] = (unsigned char)bpi;                         \
    __builtin_amdgcn_wave_barrier();                                              \
    st[lane] = state;                                                             \
    __builtin_amdgcn_wave_barrier();                                              \
  }

__global__ __launch_bounds__(64, 1) void k_fwd_bp(const float* __restrict__ pot,
                                                  const float* __restrict__ trans,
                                                  const int* __restrict__ lens_i,
                                                  unsigned char* __restrict__ bp,
                                                  float* __restrict__ fstate) {
  int b = blockIdx.x, lane = threadIdx.x;
  __shared__ float4 st4v[16];
  float* st = (float*)st4v;

  float2 t2[32];
  #pragma unroll
  for (int p = 0; p < 32; ++p)
    t2[p] = make_float2(trans[(2 * p) * N_ + lane], trans[(2 * p + 1) * N_ + lane]);

  const float* pb = pot + (size_t)b * T_ * N_;
  unsigned char* bpb = bp + (size_t)b * T_ * N_;
  int len_b = lens_i[b];

  float state = pb[lane];
  st[lane] = state;
  __builtin_amdgcn_wave_barrier();

  float p0 = pb[1 * N_ + lane];
  float p1 = pb[2 * N_ + lane];
  float p2 = pb[3 * N_ + lane];
  float p3 = pb[4 * N_ + lane];

  int t = 1;
  for (; t + 3 <= T_ - 1; t += 4) {
    FWD_STEP(t + 0, p0);
    FWD_STEP(t + 1, p1);
    FWD_STEP(t + 2, p2);
    FWD_STEP(t + 3, p3);
  }
  // tail: t = 4093, 4094, 4095
  FWD_STEP(t + 0, p0);
  FWD_STEP(t + 1, p1);
  FWD_STEP(t + 2, p2);

  fstate[b * N_ + lane] = state;
}

// ---------------- backtrace: scalar chain (readlane + uniform select) ----------------
__global__ __launch_bounds__(64, 1) void k_bwd(const unsigned char* __restrict__ bp,
                                               const float* __restrict__ fstate,
                                               const int* __restrict__ lens_i,
                                               float* __restrict__ decoded) {
  int b = blockIdx.x, lane = threadIdx.x;

  __shared__ float fv[64];
  __shared__ int sh_tag;
  fv[lane] = fstate[b * N_ + lane];
  __syncthreads();
  if (lane == 0) {
    float best = fv[0]; int tg = 0;
    for (int i = 1; i < 64; ++i) if (fv[i] > best) { best = fv[i]; tg = i; }  // first max
    sh_tag = tg;
  }
  __syncthreads();
  int s_last = __builtin_amdgcn_readfirstlane(sh_tag);
  int len_b = lens_i[b];

  const unsigned char* bpb = bp + (size_t)b * T_ * N_;
  float* dec = decoded + (size_t)b * T_;

  int s_tag = s_last;
  if (lane == 0) dec[T_ - 1] = (float)s_last;

  const int G = 32;
  int bufA[G], bufB[G];
  const int k0 = T_ - 1;
  #pragma unroll
  for (int i = 0; i < G; ++i) bufA[i] = (int)bpb[(size_t)(k0 - i) * N_ + lane];

  const int nrows = T_ - 1;          // 4095
  const int groups = nrows / G;      // 127 full groups + 31 tail

  for (int g = 0; g < groups; ++g) {
    int kn = k0 - G * (g + 1);
    #pragma unroll
    for (int i = 0; i < G; ++i)
      bufB[i] = (kn - i >= 1) ? (int)bpb[(size_t)(kn - i) * N_ + lane] : 0;

    int kbase = k0 - G * g;
    #pragma unroll
    for (int i = 0; i < G; ++i) {
      int k = kbase - i;
      int prev = __builtin_amdgcn_readlane(bufA[i], s_tag);
      int t = k - 1;
      s_tag = (t < len_b - 1) ? prev : s_last;
      if (lane == 0) dec[t] = (float)s_tag;
    }
    #pragma unroll
    for (int i = 0; i < G; ++i) bufA[i] = bufB[i];
  }

  int kbase = k0 - G * groups;
  #pragma unroll
  for (int i = 0; i < G; ++i) {
    int k = kbase - i;
    if (k >= 1) {
      int prev = __builtin_amdgcn_readlane(bufA[i], s_tag);
      int t = k - 1;
      s_tag = (t < len_b - 1) ? prev : s_last;
      if (lane == 0) dec[t] = (float)s_tag;
    }
  }
}

extern "C" void kernel_launch(void* const* d_in, const int* in_sizes, int n_in,
                              void* d_out, int out_size, void* d_ws, size_t ws_size,
                              hipStream_t stream) {
  const float* x            = (const float*)d_in[0];
  const unsigned char* mask = (const unsigned char*)d_in[1];
  const float* W            = (const float*)d_in[2];
  const float* bias         = (const float*)d_in[3];
  const float* trans        = (const float*)d_in[4];
  const float* lb           = (const float*)d_in[5];
  const float* rb           = (const float*)d_in[6];

  float* out         = (float*)d_out;
  float* out_decoded = out;                              // B*T
  float* out_pot     = out + (size_t)B_ * T_;            // B*T*N
  float* out_lens    = out_pot + (size_t)B_ * T_ * N_;   // B
  float* out_trans   = out_lens + B_;                    // N*N

  const size_t bp_bytes   = (size_t)B_ * T_ * N_;        // 16,777,216
  const size_t fstate_off = bp_bytes;
  const size_t lens_off   = fstate_off + (size_t)B_ * N_ * 4;

  unsigned char* bp = (unsigned char*)d_ws;
  float* fstate     = (float*)((char*)d_ws + fstate_off);
  int*   lens_i     = (int*)((char*)d_ws + lens_off);

  k_misc<<<68, 64, 0, stream>>>(mask, trans, out_lens, out_trans, lens_i);
  k_gemm<<<(B_ * T_) / 64, 256, 0, stream>>>(x, W, bias, lb, rb, out_pot);
  k_fwd_bp<<<B_, 64, 0, stream>>>(out_pot, trans, lens_i, bp, fstate);
  k_bwd<<<B_, 64, 0, stream>>>(bp, fstate, lens_i, out_decoded);
}

// Round 15
// 1462.224 us; speedup vs baseline: 1.8353x; 1.8353x over previous
//
#include <hip/hip_runtime.h>

#define B_ 64
#define T_ 4096
#define D_ 256
#define N_ 64

typedef float f32x16 __attribute__((ext_vector_type(16)));

// ---------------- misc: lens + trans copy ----------------
__global__ __launch_bounds__(64) void k_misc(const unsigned char* __restrict__ mask,
                                             const float* __restrict__ trans,
                                             float* __restrict__ out_lens,
                                             float* __restrict__ out_trans,
                                             int* __restrict__ lens_i) {
  int blk = blockIdx.x, lane = threadIdx.x;
  if (blk < B_) {
    int probe = (int)mask[0] + (int)mask[1] + (int)mask[2] + (int)mask[3];
    int cnt = 0;
    if (probe >= 2) {
      const unsigned char* row = mask + (size_t)blk * T_;
      for (int i = lane; i < T_; i += 64) cnt += row[i] ? 1 : 0;
    } else {
      const int* rowi = (const int*)mask + (size_t)blk * T_;
      for (int i = lane; i < T_; i += 64) cnt += rowi[i] ? 1 : 0;
    }
    #pragma unroll
    for (int off = 32; off > 0; off >>= 1) cnt += __shfl_down(cnt, off, 64);
    if (lane == 0) { out_lens[blk] = (float)cnt; lens_i[blk] = cnt; }
  } else {
    int base = (blk - B_) * 1024;
    for (int i = lane; i < 1024; i += 64) out_trans[base + i] = trans[base + i];
  }
}

// ---------------- projection: pot = x@W + b (+ boundaries), LDS-staged x ----------
// (r5 version, proven ~55us)
__global__ __launch_bounds__(256, 2) void k_gemm(const float* __restrict__ x,
                                                 const float* __restrict__ W,
                                                 const float* __restrict__ bias,
                                                 const float* __restrict__ lb,
                                                 const float* __restrict__ rb,
                                                 float* __restrict__ pot) {
  __shared__ float xs[64 * D_];            // 64 KB
  int tid = threadIdx.x;
  int wid = tid >> 6, lane = tid & 63;
  size_t row0 = (size_t)blockIdx.x * 64;

  const float* xb = x + row0 * D_;
  #pragma unroll
  for (int i = 0; i < 16; ++i) {
    int r = wid * 16 + i;
    float4 v = *reinterpret_cast<const float4*>(xb + (size_t)r * D_ + lane * 4);
    *reinterpret_cast<float4*>(&xs[r * D_ + lane * 4]) = v;
  }
  __syncthreads();

  float bv = bias[lane];
  float lbv = lb[lane];
  float rbv = rb[lane];

  float acc[16];
  #pragma unroll
  for (int r = 0; r < 16; ++r) {
    int t = (int)((row0 + wid * 16 + r) & (T_ - 1));
    float a = bv;
    if (t == 0)      a += lbv;
    if (t == T_ - 1) a += rbv;
    acc[r] = a;
  }

  #pragma unroll
  for (int c = 0; c < 4; ++c) {
    float w[64];
    #pragma unroll
    for (int k = 0; k < 64; ++k) w[k] = W[(size_t)(c * 64 + k) * N_ + lane];
    #pragma unroll
    for (int r = 0; r < 16; ++r) {
      const float4* xr = reinterpret_cast<const float4*>(&xs[(wid * 16 + r) * D_ + c * 64]);
      #pragma unroll
      for (int q = 0; q < 16; ++q) {
        float4 xv = xr[q];
        acc[r] += xv.x * w[q * 4 + 0];
        acc[r] += xv.y * w[q * 4 + 1];
        acc[r] += xv.z * w[q * 4 + 2];
        acc[r] += xv.w * w[q * 4 + 3];
      }
    }
  }

  #pragma unroll
  for (int r = 0; r < 16; ++r)
    pot[(row0 + wid * 16 + r) * N_ + lane] = acc[r];
}

// ---------------- phase 1: forward values only (r3 structure, ~1100us, FROZEN) ----
#define FWD_STEP(TIDX, PREG)                                                      \
  {                                                                               \
    float pot_t = PREG;                                                           \
    int tp = (TIDX) + 4; if (tp > T_ - 1) tp = T_ - 1;                            \
    PREG = pb[(size_t)tp * N_ + lane];                                            \
    float m[64];                                                                  \
    _Pragma("unroll")                                                             \
    for (int g = 0; g < 16; ++g) {                                                \
      float4 s4 = st4v[g];                                                        \
      float2 ca = make_float2(s4.x, s4.y) + t2[2 * g];                            \
      float2 cb = make_float2(s4.z, s4.w) + t2[2 * g + 1];                        \
      m[4 * g + 0] = ca.x; m[4 * g + 1] = ca.y;                                   \
      m[4 * g + 2] = cb.x; m[4 * g + 3] = cb.y;                                   \
    }                                                                             \
    float r1[22];                                                                 \
    _Pragma("unroll")                                                             \
    for (int i = 0; i < 21; ++i)                                                  \
      r1[i] = fmaxf(fmaxf(m[3 * i], m[3 * i + 1]), m[3 * i + 2]);                 \
    r1[21] = m[63];                                                               \
    float r2[8];                                                                  \
    _Pragma("unroll")                                                             \
    for (int i = 0; i < 7; ++i)                                                   \
      r2[i] = fmaxf(fmaxf(r1[3 * i], r1[3 * i + 1]), r1[3 * i + 2]);              \
    r2[7] = r1[21];                                                               \
    float r3a = fmaxf(fmaxf(r2[0], r2[1]), r2[2]);                                \
    float r3b = fmaxf(fmaxf(r2[3], r2[4]), r2[5]);                                \
    float r3c = fmaxf(r2[6], r2[7]);                                              \
    float best = fmaxf(fmaxf(r3a, r3b), r3c);                                     \
    float ns = pot_t + best;                                                      \
    state = ((TIDX) < len_b) ? ns : state;                                        \
    sb[(size_t)(TIDX) * N_ + lane] = state;                                       \
    __builtin_amdgcn_wave_barrier();                                              \
    st[lane] = state;                                                             \
    __builtin_amdgcn_wave_barrier();                                              \
  }

__global__ __launch_bounds__(64, 1) void k_fwd_states(const float* __restrict__ pot,
                                                      const float* __restrict__ trans,
                                                      const int* __restrict__ lens_i,
                                                      float* __restrict__ states,
                                                      float* __restrict__ fstate) {
  int b = blockIdx.x, lane = threadIdx.x;
  __shared__ float4 st4v[16];
  float* st = (float*)st4v;

  float2 t2[32];
  #pragma unroll
  for (int p = 0; p < 32; ++p)
    t2[p] = make_float2(trans[(2 * p) * N_ + lane], trans[(2 * p + 1) * N_ + lane]);

  const float* pb = pot + (size_t)b * T_ * N_;
  float* sb = states + (size_t)b * T_ * N_;
  int len_b = lens_i[b];

  float state = pb[lane];
  st[lane] = state;
  sb[lane] = state;                      // states[t=0]
  __builtin_amdgcn_wave_barrier();

  float p0 = pb[1 * N_ + lane];
  float p1 = pb[2 * N_ + lane];
  float p2 = pb[3 * N_ + lane];
  float p3 = pb[4 * N_ + lane];

  int t = 1;
  for (; t + 3 <= T_ - 1; t += 4) {
    FWD_STEP(t + 0, p0);
    FWD_STEP(t + 1, p1);
    FWD_STEP(t + 2, p2);
    FWD_STEP(t + 3, p3);
  }
  // tail: t = 4093, 4094, 4095
  FWD_STEP(t + 0, p0);
  FWD_STEP(t + 1, p1);
  FWD_STEP(t + 2, p2);

  fstate[b * N_ + lane] = state;
}

// ---------------- phase 2: backpointers, LDS-cached trans, 4 waves x 16 t ---------
// Block stages the full 16KB trans into LDS once (coalesced float4). Each wave
// fills its register tcol from LDS (conflict-free b32, once, reused over 16 t),
// then per t: uniform 256B states-row read + r9-verified dual-chain first-index
// scan. Global trans traffic: 4.3GB -> 67MB. 16k waves = 16/SIMD TLP.
__global__ __launch_bounds__(256) void k_bp(const float* __restrict__ states,
                                            const float* __restrict__ trans,
                                            unsigned char* __restrict__ bp) {
  __shared__ float ltr[64 * 64];           // 16 KB, row-major trans copy

  const int nchunk = T_ / 64;              // 64 t per block
  int blk = blockIdx.x;
  int b = blk / nchunk;
  int chunk = blk - b * nchunk;
  int tid = threadIdx.x;
  int wid = tid >> 6, lane = tid & 63;

  // cooperative stage: 4096 floats, 256 threads x 4 float4, coalesced
  {
    const float4* src = reinterpret_cast<const float4*>(trans);
    float4* dst = reinterpret_cast<float4*>(ltr);
    #pragma unroll
    for (int i = 0; i < 4; ++i) dst[tid + 256 * i] = src[tid + 256 * i];
  }
  __syncthreads();

  // per-wave register tcol from LDS: tcol[p] = trans[p][lane] (conflict-free)
  float tcol[64];
  #pragma unroll
  for (int p = 0; p < 64; ++p) tcol[p] = ltr[p * 64 + lane];

  int t0 = chunk * 64 + wid * 16;          // this wave: t in [t0, t0+16)
  int tstart = (t0 == 0) ? 1 : t0;
  int tend = t0 + 16;

  const float* sbase = states + (size_t)b * T_ * N_;

  for (int t = tstart; t < tend; ++t) {
    const f32x16* sr = reinterpret_cast<const f32x16*>(sbase + (size_t)(t - 1) * N_);
    f32x16 s0 = sr[0];
    f32x16 s1 = sr[1];
    f32x16 s2 = sr[2];
    f32x16 s3 = sr[3];

    // chain A: p = 0..31 (r9 semantics)
    float bestA = s0[0] + tcol[0]; int iA = 0;
    #pragma unroll
    for (int j = 1; j < 16; ++j) {
      float c = s0[j] + tcol[j];
      if (c > bestA) { bestA = c; iA = j; }
    }
    #pragma unroll
    for (int j = 0; j < 16; ++j) {
      float c = s1[j] + tcol[16 + j];
      if (c > bestA) { bestA = c; iA = 16 + j; }
    }

    // chain B: p = 32..63
    float bestB = s2[0] + tcol[32]; int iB = 32;
    #pragma unroll
    for (int j = 1; j < 16; ++j) {
      float c = s2[j] + tcol[32 + j];
      if (c > bestB) { bestB = c; iB = 32 + j; }
    }
    #pragma unroll
    for (int j = 0; j < 16; ++j) {
      float c = s3[j] + tcol[48 + j];
      if (c > bestB) { bestB = c; iB = 48 + j; }
    }

    int bpi = (bestB > bestA) ? iB : iA;   // ties -> A (smaller index) = first max

    bp[((size_t)b * T_ + t) * N_ + lane] = (unsigned char)bpi;
  }
}

// ---------------- backtrace: scalar chain (readlane + uniform select) ----------------
__global__ __launch_bounds__(64, 1) void k_bwd(const unsigned char* __restrict__ bp,
                                               const float* __restrict__ fstate,
                                               const int* __restrict__ lens_i,
                                               float* __restrict__ decoded) {
  int b = blockIdx.x, lane = threadIdx.x;

  __shared__ float fv[64];
  __shared__ int sh_tag;
  fv[lane] = fstate[b * N_ + lane];
  __syncthreads();
  if (lane == 0) {
    float best = fv[0]; int tg = 0;
    for (int i = 1; i < 64; ++i) if (fv[i] > best) { best = fv[i]; tg = i; }  // first max
    sh_tag = tg;
  }
  __syncthreads();
  int s_last = __builtin_amdgcn_readfirstlane(sh_tag);
  int len_b = lens_i[b];

  const unsigned char* bpb = bp + (size_t)b * T_ * N_;
  float* dec = decoded + (size_t)b * T_;

  int s_tag = s_last;
  if (lane == 0) dec[T_ - 1] = (float)s_last;

  const int G = 32;
  int bufA[G], bufB[G];
  const int k0 = T_ - 1;
  #pragma unroll
  for (int i = 0; i < G; ++i) bufA[i] = (int)bpb[(size_t)(k0 - i) * N_ + lane];

  const int nrows = T_ - 1;          // 4095
  const int groups = nrows / G;      // 127 full groups + 31 tail

  for (int g = 0; g < groups; ++g) {
    int kn = k0 - G * (g + 1);
    #pragma unroll
    for (int i = 0; i < G; ++i)
      bufB[i] = (kn - i >= 1) ? (int)bpb[(size_t)(kn - i) * N_ + lane] : 0;

    int kbase = k0 - G * g;
    #pragma unroll
    for (int i = 0; i < G; ++i) {
      int k = kbase - i;
      int prev = __builtin_amdgcn_readlane(bufA[i], s_tag);
      int t = k - 1;
      s_tag = (t < len_b - 1) ? prev : s_last;
      if (lane == 0) dec[t] = (float)s_tag;
    }
    #pragma unroll
    for (int i = 0; i < G; ++i) bufA[i] = bufB[i];
  }

  int kbase = k0 - G * groups;
  #pragma unroll
  for (int i = 0; i < G; ++i) {
    int k = kbase - i;
    if (k >= 1) {
      int prev = __builtin_amdgcn_readlane(bufA[i], s_tag);
      int t = k - 1;
      s_tag = (t < len_b - 1) ? prev : s_last;
      if (lane == 0) dec[t] = (float)s_tag;
    }
  }
}

extern "C" void kernel_launch(void* const* d_in, const int* in_sizes, int n_in,
                              void* d_out, int out_size, void* d_ws, size_t ws_size,
                              hipStream_t stream) {
  const float* x            = (const float*)d_in[0];
  const unsigned char* mask = (const unsigned char*)d_in[1];
  const float* W            = (const float*)d_in[2];
  const float* bias         = (const float*)d_in[3];
  const float* trans        = (const float*)d_in[4];
  const float* lb           = (const float*)d_in[5];
  const float* rb           = (const float*)d_in[6];

  float* out         = (float*)d_out;
  float* out_decoded = out;                              // B*T
  float* out_pot     = out + (size_t)B_ * T_;            // B*T*N
  float* out_lens    = out_pot + (size_t)B_ * T_ * N_;   // B
  float* out_trans   = out_lens + B_;                    // N*N

  const size_t bp_bytes   = (size_t)B_ * T_ * N_;        // 16,777,216
  const size_t fstate_off = bp_bytes;
  const size_t lens_off   = fstate_off + (size_t)B_ * N_ * 4;
  const size_t states_off = lens_off + 256;

  unsigned char* bp = (unsigned char*)d_ws;
  float* fstate     = (float*)((char*)d_ws + fstate_off);
  int*   lens_i     = (int*)((char*)d_ws + lens_off);
  float* states     = (float*)((char*)d_ws + states_off);

  k_misc<<<68, 64, 0, stream>>>(mask, trans, out_lens, out_trans, lens_i);
  k_gemm<<<(B_ * T_) / 64, 256, 0, stream>>>(x, W, bias, lb, rb, out_pot);
  k_fwd_states<<<B_, 64, 0, stream>>>(out_pot, trans, lens_i, states, fstate);
  k_bp<<<B_ * (T_ / 64), 256, 0, stream>>>(states, trans, bp);
  k_bwd<<<B_, 64, 0, stream>>>(bp, fstate, lens_i, out_decoded);
}